// Round 7
// baseline (1078.391 us; speedup 1.0000x reference)
//
#include <hip/hip_runtime.h>
#include <hip/hip_bf16.h>
#include <stdint.h>

#define IGNORE_INDEX (-100)

constexpr int kB2 = 8, kT = 1024, kH = 2048, kV = 32000;
constexpr int kM = kB2 * kT;           // 8192 token rows
constexpr int BM = 256, BN = 256, BK = 64;
constexpr int NSPLIT = 125;            // vocab splits (1 N-tile each)
constexpr int MBLKS = kM / BM;         // 32 row blocks
constexpr int KT = kH / BK;            // 32 K-tiles
constexpr int NWG = NSPLIT * MBLKS;    // 4000 workgroups

typedef __bf16 bf16_t;
typedef __bf16 bf16x8 __attribute__((ext_vector_type(8)));
typedef float  f32x4  __attribute__((ext_vector_type(4)));

// ---------------- cast fp32 -> bf16 (vectorized) ----------------
__global__ void cast_to_bf16(const float* __restrict__ src, uint2* __restrict__ dst, int n4) {
  int idx = blockIdx.x * blockDim.x + threadIdx.x;
  int stride = gridDim.x * blockDim.x;
  const float4* s = (const float4*)src;
  for (int i = idx; i < n4; i += stride) {
    float4 v = s[i];
    union { bf16_t h[4]; uint2 u; } p;
    p.h[0] = (bf16_t)v.x; p.h[1] = (bf16_t)v.y;
    p.h[2] = (bf16_t)v.z; p.h[3] = (bf16_t)v.w;
    dst[i] = p.u;
  }
}

__device__ __forceinline__ void gload_lds16(const void* g, void* l) {
  __builtin_amdgcn_global_load_lds(
      (const __attribute__((address_space(1))) void*)g,
      (__attribute__((address_space(3))) void*)l, 16, 0, 0);
}

// ---------------- fused GEMM + logsumexp + target grab ----------------
// 256x256x64 tile, 8 waves (4M x 2N), 2 LDS dbuf, 4 phases/K-tile, 2 barriers
// per phase, setprio around MFMA (T5). COUNTED vmcnt (T4):
//   per-wave load queue per tile t (program order):
//     ph0: A(t+1) x4   |  ph1: B-h0(t+1) x2, B-h1(t+1) x2
//   ph0 reads B rows [0,128) only; ph1/ph3 read rows [128,256) (col remap),
//   so at ph3-end only A(t+1)+B-h0(t+1) must have landed -> vmcnt(2)
//   (B-h1(t+1) flies on; forced at t+1 ph0-end -> vmcnt(4)). Never 0 in
//   steady state; tails (t==KT-1) fall back to vmcnt(0) where required.
// LDS layout: linear [row][8 chunks of 16B]; chunk (row,j) holds global chunk
// (row, j^(row&7)) — pre-swizzled source, swizzled read (rule #21, involution).
// Block->(split,mblk) map: each XCD owns 4 A-panels and sweeps 8 splits per
// panel consecutively (A stays L2-resident; each W slice on exactly one XCD).
__global__ __launch_bounds__(512, 2) void fused_lse(
    const bf16_t* __restrict__ Wb,   // [V][H] bf16
    const bf16_t* __restrict__ Ab,   // [M][H] bf16
    const float* __restrict__ bias,  // [V]
    const int* __restrict__ target,  // [M]
    float4* __restrict__ partials)   // [NSPLIT][M] : (m, s, tgt_logit, 0)
{
  const int bid = blockIdx.x;
  const int gg = bid >> 8, r = bid & 255;
  int split, mblk;
  if (gg < 15) { int j = r >> 3; split = gg * 8 + (j & 7); mblk = (r & 7) * 4 + (j >> 3); }
  else         { split = 120 + (r >> 5); mblk = r & 31; }   // last group: 5 splits x 32

  const int tid = threadIdx.x;
  const int lane = tid & 63;
  const int w  = tid >> 6;     // 0..7
  const int wm = w >> 1;       // 0..3 : 64-row band
  const int wn = w & 1;        // 0..1 : 64-col slot within each 128-col half
  const int g  = lane >> 4;
  const int li = lane & 15;
  const int rowbase = mblk * BM;
  const int n0 = split * BN;

  __shared__ __align__(16) uint8_t lds[2][65536];   // per buf: A 32KB | B 32KB

  f32x4 acc[4][8];   // [m][n]: n<4 -> cols wn*64+n*16 ; n>=4 -> 128+wn*64+(n-4)*16
  const f32x4 vzero = {0.f, 0.f, 0.f, 0.f};
#pragma unroll
  for (int m = 0; m < 4; ++m)
#pragma unroll
    for (int n = 0; n < 8; ++n) acc[m][n] = vzero;

  // staging geometry. A: 32 segs of 1KB, wave w owns segs 4w..4w+3.
  // B: 32 segs; half0 = segs 0..15, half1 = segs 16..31; wave w owns
  // {2w,2w+1} (h0) then {16+2w,16+2w+1} (h1) — ISSUE ORDER h0 first.
  // chunk c = seg*64+lane; row=c>>3, col=c&7; source col ^= row&7.
  int goffA[4], lofsA[4], goffB[4], lofsB[4];
#pragma unroll
  for (int it = 0; it < 4; ++it) {
    int seg = 4 * w + it, c = seg * 64 + lane;
    int row = c >> 3, col = c & 7;
    goffA[it] = row * (kH * 2) + ((col ^ (row & 7)) << 4);
    lofsA[it] = seg * 1024;
  }
#pragma unroll
  for (int it = 0; it < 4; ++it) {
    int seg = (it < 2) ? (2 * w + it) : (16 + 2 * w + (it - 2));
    int c = seg * 64 + lane;
    int row = c >> 3, col = c & 7;
    goffB[it] = row * (kH * 2) + ((col ^ (row & 7)) << 4);
    lofsB[it] = 32768 + seg * 1024;
  }

  const uint8_t* Agp = (const uint8_t*)(Ab + (size_t)rowbase * kH);
  const uint8_t* Bgp = (const uint8_t*)(Wb + (size_t)n0 * kH);

  // prologue: stage tile 0 into buf 0, drain
#pragma unroll
  for (int it = 0; it < 4; ++it) gload_lds16(Agp + goffA[it], lds[0] + lofsA[it]);
#pragma unroll
  for (int it = 0; it < 4; ++it) gload_lds16(Bgp + goffB[it], lds[0] + lofsB[it]);
  asm volatile("s_waitcnt vmcnt(0)" ::: "memory");
  __builtin_amdgcn_s_barrier();

  for (int t = 0; t < KT; ++t) {
    const uint8_t* As = lds[t & 1];
    const uint8_t* Bs = lds[t & 1] + 32768;
    uint8_t* Ld = lds[(t + 1) & 1];
    const int kb = (t + 1) << 7;         // next tile's K byte offset
    const bool pf = (t + 1 < KT);        // workgroup-uniform
    const bool last = (t == KT - 1);
    bf16x8 af[4], bfv[4];

    // ---- phase 0: ks=0, B rows [0,128); stage A(t+1) ----
#pragma unroll
    for (int m = 0; m < 4; ++m) {
      int row = wm * 64 + m * 16 + li;
      af[m] = *(const bf16x8*)(As + row * 128 + ((g ^ (row & 7)) << 4));
    }
#pragma unroll
    for (int n = 0; n < 4; ++n) {
      int row = wn * 64 + n * 16 + li;
      bfv[n] = *(const bf16x8*)(Bs + row * 128 + ((g ^ (row & 7)) << 4));
    }
    if (pf) {
#pragma unroll
      for (int it = 0; it < 4; ++it) gload_lds16(Agp + goffA[it] + kb, Ld + lofsA[it]);
    }
    __builtin_amdgcn_s_barrier();
    __builtin_amdgcn_s_setprio(1);
#pragma unroll
    for (int m = 0; m < 4; ++m)
#pragma unroll
      for (int n = 0; n < 4; ++n)
        acc[m][n] = __builtin_amdgcn_mfma_f32_16x16x32_bf16(af[m], bfv[n], acc[m][n], 0, 0, 0);
    __builtin_amdgcn_s_setprio(0);
    // force B-h1(t) landed (issued t-1 ph1, ~3 phases flight); A(t+1) flies on
    if (last) asm volatile("s_waitcnt vmcnt(0)" ::: "memory");
    else      asm volatile("s_waitcnt vmcnt(4)" ::: "memory");
    __builtin_amdgcn_s_barrier();

    // ---- phase 1: ks=0, B rows [128,256); stage B(t+1) (h0 pair, h1 pair) ----
#pragma unroll
    for (int n = 0; n < 4; ++n) {
      int row = 128 + wn * 64 + n * 16 + li;
      bfv[n] = *(const bf16x8*)(Bs + row * 128 + ((g ^ (row & 7)) << 4));
    }
    if (pf) {
#pragma unroll
      for (int it = 0; it < 4; ++it) gload_lds16(Bgp + goffB[it] + kb, Ld + lofsB[it]);
    }
    __builtin_amdgcn_s_barrier();
    __builtin_amdgcn_s_setprio(1);
#pragma unroll
    for (int m = 0; m < 4; ++m)
#pragma unroll
      for (int n = 0; n < 4; ++n)
        acc[m][4 + n] = __builtin_amdgcn_mfma_f32_16x16x32_bf16(af[m], bfv[n], acc[m][4 + n], 0, 0, 0);
    __builtin_amdgcn_s_setprio(0);
    __builtin_amdgcn_s_barrier();

    // ---- phase 2: ks=1, B rows [0,128) ----
#pragma unroll
    for (int m = 0; m < 4; ++m) {
      int row = wm * 64 + m * 16 + li;
      af[m] = *(const bf16x8*)(As + row * 128 + (((4 + g) ^ (row & 7)) << 4));
    }
#pragma unroll
    for (int n = 0; n < 4; ++n) {
      int row = wn * 64 + n * 16 + li;
      bfv[n] = *(const bf16x8*)(Bs + row * 128 + (((4 + g) ^ (row & 7)) << 4));
    }
    __builtin_amdgcn_s_barrier();
    __builtin_amdgcn_s_setprio(1);
#pragma unroll
    for (int m = 0; m < 4; ++m)
#pragma unroll
      for (int n = 0; n < 4; ++n)
        acc[m][n] = __builtin_amdgcn_mfma_f32_16x16x32_bf16(af[m], bfv[n], acc[m][n], 0, 0, 0);
    __builtin_amdgcn_s_setprio(0);
    __builtin_amdgcn_s_barrier();

    // ---- phase 3: ks=1, B rows [128,256); counted wait for tile t+1 ----
#pragma unroll
    for (int n = 0; n < 4; ++n) {
      int row = 128 + wn * 64 + n * 16 + li;
      bfv[n] = *(const bf16x8*)(Bs + row * 128 + (((4 + g) ^ (row & 7)) << 4));
    }
    __builtin_amdgcn_s_barrier();
    __builtin_amdgcn_s_setprio(1);
#pragma unroll
    for (int m = 0; m < 4; ++m)
#pragma unroll
      for (int n = 0; n < 4; ++n)
        acc[m][4 + n] = __builtin_amdgcn_mfma_f32_16x16x32_bf16(af[m], bfv[n], acc[m][4 + n], 0, 0, 0);
    __builtin_amdgcn_s_setprio(0);
    // force A(t+1)+B-h0(t+1) landed; B-h1(t+1) (2 newest) stays in flight
    if (pf) asm volatile("s_waitcnt vmcnt(2)" ::: "memory");
    __builtin_amdgcn_s_barrier();
  }

  // ---- epilogue (once per block): bias + LSE partial + target grab ----
  float bv[8];
#pragma unroll
  for (int n = 0; n < 8; ++n)
    bv[n] = bias[n0 + ((n >> 2) << 7) + wn * 64 + (n & 3) * 16 + li];

  float4* mrg = (float4*)lds[0];   // [256 rows][2 wn] — all vmem drained (t=KT-1 waits)
#pragma unroll
  for (int m = 0; m < 4; ++m)
#pragma unroll
    for (int i = 0; i < 4; ++i) {
#pragma unroll
      for (int n = 0; n < 8; ++n) acc[m][n][i] += bv[n];
      float tmax = acc[m][0][i];
#pragma unroll
      for (int n = 1; n < 8; ++n) tmax = fmaxf(tmax, acc[m][n][i]);
#pragma unroll
      for (int d = 1; d <= 8; d <<= 1) tmax = fmaxf(tmax, __shfl_xor(tmax, d));
      float tsum = 0.f;
#pragma unroll
      for (int n = 0; n < 8; ++n) tsum += __expf(acc[m][n][i] - tmax);
#pragma unroll
      for (int d = 1; d <= 8; d <<= 1) tsum += __shfl_xor(tsum, d);
      int trow = rowbase + wm * 64 + m * 16 + g * 4 + i;
      int tv = target[trow];
      int c = ((tv == IGNORE_INDEX) ? 0 : tv) - n0;   // col within [0,256)?
      float rt = 0.f;
#pragma unroll
      for (int n = 0; n < 8; ++n) {
        int col16 = wn * 4 + (n & 3) + ((n >> 2) << 3);  // (col/16) of frag n
        rt += ((c >> 4) == col16 && (c & 15) == li) ? acc[m][n][i] : 0.f;
      }
#pragma unroll
      for (int d = 1; d <= 8; d <<= 1) rt += __shfl_xor(rt, d);
      if (li == 0) {
        int lr = wm * 64 + m * 16 + g * 4 + i;
        mrg[lr * 2 + wn] = float4{tmax, tsum, rt, 0.f};
      }
    }
  __syncthreads();
  if (tid < BM) {
    float4 p0 = mrg[tid * 2 + 0], p1 = mrg[tid * 2 + 1];
    float mm = fmaxf(p0.x, p1.x);
    float ss = p0.y * __expf(p0.x - mm) + p1.y * __expf(p1.x - mm);
    partials[(size_t)split * kM + rowbase + tid] = float4{mm, ss, p0.z + p1.z, 0.f};
  }
}

// ---------------- combine split partials -> per-token logp ----------------
// one wave per row; 64 lanes strided over splits, shfl LSE-merge. grid = kM/4.
__global__ __launch_bounds__(256) void combine_lse(
    const float4* __restrict__ partials, float* __restrict__ per_tok, int nsplit)
{
  int row  = blockIdx.x * 4 + (threadIdx.x >> 6);
  int lane = threadIdx.x & 63;
  float m = -1e30f, s = 0.f, t = 0.f;
  for (int sp = lane; sp < nsplit; sp += 64) {
    float4 p = partials[(size_t)sp * kM + row];
    t += p.z;
    float nm = fmaxf(m, p.x);
    s = s * __expf(m - nm) + p.y * __expf(p.x - nm);
    m = nm;
  }
#pragma unroll
  for (int d = 1; d < 64; d <<= 1) {
    float mo = __shfl_xor(m, d), so = __shfl_xor(s, d), to = __shfl_xor(t, d);
    float nm = fmaxf(m, mo);
    s = s * __expf(m - nm) + so * __expf(mo - nm);
    m = nm; t += to;
  }
  if (lane == 0) per_tok[row] = t - (m + logf(s));
}

// ---------------- final scalar loss ----------------
__global__ __launch_bounds__(1024) void final_loss(
    const float* __restrict__ per_tok, const int* __restrict__ target, float* __restrict__ out)
{
  __shared__ float redv[16], redc[16];
  __shared__ float ssum[8], scnt[8];
  int t = threadIdx.x;
  int wid = t >> 6, lane = t & 63;
  for (int b = 0; b < 8; ++b) {
    int row = b * 1024 + t;
    float mk = (target[row] != IGNORE_INDEX) ? 1.f : 0.f;
    float v = per_tok[row] * mk;
#pragma unroll
    for (int d = 1; d <= 32; d <<= 1) { v += __shfl_xor(v, d); mk += __shfl_xor(mk, d); }
    if (lane == 0) { redv[wid] = v; redc[wid] = mk; }
    __syncthreads();
    if (t == 0) {
      float sv = 0.f, sc = 0.f;
      for (int j = 0; j < 16; ++j) { sv += redv[j]; sc += redc[j]; }
      ssum[b] = sv; scnt[b] = sc;
    }
    __syncthreads();
  }
  if (t == 0) {
    float nsum = 0.f, ncnt = 0.f;
    for (int b = 0; b < 4; ++b) { nsum += ssum[b]; ncnt += scnt[b]; }
    float nll = -nsum / ncnt;
    float pref = 0.f;
    for (int b = 0; b < 4; ++b) {
      float avc = ssum[b] / scnt[b];
      float avr = ssum[b + 4] / scnt[b + 4];
      float d = 0.1f * (avc - avr);                 // BETA = 0.1
      float ls = (d >= 0.f) ? -log1pf(__expf(-d)) : d - log1pf(__expf(d));
      pref += ls;
    }
    pref *= 0.25f;                                  // mean over 4 pairs
    out[0] = 1.0f * nll - pref;                     // ALPHA = 1.0
  }
}

extern "C" void kernel_launch(void* const* d_in, const int* in_sizes, int n_in,
                              void* d_out, int out_size, void* d_ws, size_t ws_size,
                              hipStream_t stream) {
  const float* lin_weight = (const float*)d_in[0];  // [V][H]
  const float* input      = (const float*)d_in[1];  // [B2][T][H]
  const int*   target     = (const int*)d_in[2];    // [B2][T]
  const float* bias       = (const float*)d_in[3];  // [V]
  float* out = (float*)d_out;

  uint8_t* ws = (uint8_t*)d_ws;
  size_t offW = 0;
  size_t offA = offW + (size_t)kV * kH * 2;            // 131,072,000 B
  size_t offP = offA + (size_t)kM * kH * 2;            // +33,554,432 B
  size_t offT = offP + (size_t)NSPLIT * kM * 16;       // +16,384,000 B
  size_t need = offT + (size_t)kM * 4;
  if (ws_size < need) return;  // clean failure signal (output stays 0)

  bf16_t* Wb = (bf16_t*)(ws + offW);
  bf16_t* Ab = (bf16_t*)(ws + offA);
  float4* partials = (float4*)(ws + offP);
  float*  per_tok  = (float*)(ws + offT);

  cast_to_bf16<<<2048, 256, 0, stream>>>(lin_weight, (uint2*)Wb, kV * kH / 4);
  cast_to_bf16<<<1024, 256, 0, stream>>>(input, (uint2*)Ab, kM * kH / 4);
  fused_lse<<<NWG, 512, 0, stream>>>(Wb, Ab, bias, target, partials);
  combine_lse<<<kM / 4, 256, 0, stream>>>(partials, per_tok, NSPLIT);
  final_loss<<<1, 1024, 0, stream>>>(per_tok, target, out);
}

// Round 8
// 790.125 us; speedup vs baseline: 1.3648x; 1.3648x over previous
//
#include <hip/hip_runtime.h>
#include <hip/hip_bf16.h>
#include <stdint.h>

#define IGNORE_INDEX (-100)

constexpr int kB2 = 8, kT = 1024, kH = 2048, kV = 32000;
constexpr int kM = kB2 * kT;           // 8192 token rows
constexpr int BM = 256, BN = 256, BK = 128;   // fp8: 128-B rows, same LDS bytes as bf16@64
constexpr int NSPLIT = 125;            // vocab splits (1 N-tile each)
constexpr int MBLKS = kM / BM;         // 32 row blocks
constexpr int KT = kH / BK;            // 16 K-tiles
constexpr int NWG = NSPLIT * MBLKS;    // 4000 workgroups

typedef int   i32x4  __attribute__((ext_vector_type(4)));
typedef int   i32x8  __attribute__((ext_vector_type(8)));
typedef float f32x16 __attribute__((ext_vector_type(16)));

// ---------------- cast fp32 -> fp8 e4m3 (OCP), optional pre-scale ----------------
// packs 8 floats -> 8 fp8 bytes via v_cvt_pk_fp8_f32 (RNE, saturating)
__global__ void cast_to_fp8(const float* __restrict__ src, uint2* __restrict__ dst,
                            int n8, float scale) {
  int idx = blockIdx.x * blockDim.x + threadIdx.x;
  int stride = gridDim.x * blockDim.x;
  const float4* s = (const float4*)src;
  for (int i = idx; i < n8; i += stride) {
    float4 v0 = s[2 * i], v1 = s[2 * i + 1];
    int lo = 0, hi = 0;
    lo = __builtin_amdgcn_cvt_pk_fp8_f32(v0.x * scale, v0.y * scale, lo, false);
    lo = __builtin_amdgcn_cvt_pk_fp8_f32(v0.z * scale, v0.w * scale, lo, true);
    hi = __builtin_amdgcn_cvt_pk_fp8_f32(v1.x * scale, v1.y * scale, hi, false);
    hi = __builtin_amdgcn_cvt_pk_fp8_f32(v1.z * scale, v1.w * scale, hi, true);
    dst[i] = uint2{(unsigned)lo, (unsigned)hi};
  }
}

__device__ __forceinline__ void gload_lds16(const void* g, void* l) {
  __builtin_amdgcn_global_load_lds(
      (const __attribute__((address_space(1))) void*)g,
      (__attribute__((address_space(3))) void*)l, 16, 0, 0);
}

// ---------------- fused fp8 GEMM + logsumexp + target grab ----------------
// 256x256x128 tile, 8 waves (4M x 2N; wave = 64 rows x 128 cols), 2 LDS dbuf.
// MFMA: mfma_scale_f32_32x32x64_f8f6f4 (fp8 x fp8, unit e8m0 scales 0x7F).
// Wave frags: 2 (M, 32) x 4 (N, 32); per K-tile 2 K-slices of 64 -> 16 MFMA.
// 4 phases/K-tile (ks x n-half), 2 barriers each, setprio around MFMA (T5),
// stage A at ph0 / B at ph1, vmcnt(0) drain at ph3 (proven-neutral vs counted).
// LDS layout per buffer: A[256][128B] | B[256][128B]; chunk (row,j) holds
// global chunk (row, j^(row&7)) — pre-swizzled source, swizzled read (#21).
// Operand layout 32x32x64: lane l holds row=l&31 (A) / col=l&31 (B),
// k = (l>>5)*32 + [0..31] (K-contiguous, 2x b128). C: col=l&31,
// row32 = (r&3) + 8*(r>>2) + 4*(l>>5)  [m74/m101, dtype-independent].
// Block->(split,mblk) map unchanged (XCD-affinity; FETCH 775MB proven r6).
__global__ __launch_bounds__(512, 2) void fused_lse(
    const uint8_t* __restrict__ Wb,  // [V][H] fp8 (pre-scaled by 64)
    const uint8_t* __restrict__ Ab,  // [M][H] fp8
    const float* __restrict__ bias,  // [V]
    const int* __restrict__ target,  // [M]
    float4* __restrict__ partials)   // [NSPLIT][M] : (m, s, tgt_logit, 0)
{
  const int bid = blockIdx.x;
  const int gg = bid >> 8, r = bid & 255;
  int split, mblk;
  if (gg < 15) { int j = r >> 3; split = gg * 8 + (j & 7); mblk = (r & 7) * 4 + (j >> 3); }
  else         { split = 120 + (r >> 5); mblk = r & 31; }   // last group: 5 splits x 32

  const int tid = threadIdx.x;
  const int lane = tid & 63;
  const int w   = tid >> 6;     // 0..7
  const int wm  = w >> 1;       // 0..3 : 64-row band
  const int wn  = w & 1;        // 0..1 : 128-col half
  const int h   = lane >> 5;    // k-half of operand
  const int l31 = lane & 31;
  const int rowbase = mblk * BM;
  const int n0 = split * BN;

  __shared__ __align__(16) uint8_t lds[2][65536];   // per buf: A 32KB | B 32KB

  f32x16 acc[2][4];
#pragma unroll
  for (int m = 0; m < 2; ++m)
#pragma unroll
    for (int n = 0; n < 4; ++n)
#pragma unroll
      for (int q = 0; q < 16; ++q) acc[m][n][q] = 0.f;

  // staging geometry (identical for A and B tiles: 32 segs of 1KB each;
  // wave w owns segs 4w..4w+3). chunk c = seg*64+lane; row=c>>3, col=c&7;
  // global source col ^= row&7 (involution).
  int goff[4], lofs[4];
#pragma unroll
  for (int it = 0; it < 4; ++it) {
    int seg = 4 * w + it, c = seg * 64 + lane;
    int row = c >> 3, col = c & 7;
    goff[it] = row * kH + ((col ^ (row & 7)) << 4);   // fp8: row stride = kH bytes
    lofs[it] = seg * 1024;
  }

  const uint8_t* Agp = Ab + (size_t)rowbase * kH;
  const uint8_t* Bgp = Wb + (size_t)n0 * kH;

  // fragment read rows
  int raM[2], rbN[4];
#pragma unroll
  for (int m = 0; m < 2; ++m) raM[m] = wm * 64 + m * 32 + l31;
#pragma unroll
  for (int n = 0; n < 4; ++n) rbN[n] = wn * 128 + n * 32 + l31;

  // read one 32B operand frag (2x b128, chunks c0,c0+1 with XOR swizzle)
  auto RD = [&](const uint8_t* base, int rr, int ks) -> i32x8 {
    int c0 = ks * 4 + h * 2;
    union { i32x4 q[2]; i32x8 o; } u;
    u.q[0] = *(const i32x4*)(base + rr * 128 + ((c0 ^ (rr & 7)) << 4));
    u.q[1] = *(const i32x4*)(base + rr * 128 + (((c0 + 1) ^ (rr & 7)) << 4));
    return u.o;
  };

#define MFMA8(am, bn, cc) \
  __builtin_amdgcn_mfma_scale_f32_32x32x64_f8f6f4((am), (bn), (cc), 0, 0, \
      0, 0x7F7F7F7F, 0, 0x7F7F7F7F)

  // prologue: stage tile 0 into buf 0, drain
#pragma unroll
  for (int it = 0; it < 4; ++it) gload_lds16(Agp + goff[it], lds[0] + lofs[it]);
#pragma unroll
  for (int it = 0; it < 4; ++it) gload_lds16(Bgp + goff[it], lds[0] + 32768 + lofs[it]);
  asm volatile("s_waitcnt vmcnt(0)" ::: "memory");
  __builtin_amdgcn_s_barrier();

  for (int t = 0; t < KT; ++t) {
    const uint8_t* As = lds[t & 1];
    const uint8_t* Bs = lds[t & 1] + 32768;
    uint8_t* Ld = lds[(t + 1) & 1];
    const int kb = (t + 1) << 7;         // next tile's K byte offset (128 B)
    const bool pf = (t + 1 < KT);        // workgroup-uniform
    i32x8 a0, a1, b0, b1;

    // ---- phase 0: ks=0, n=0,1; stage A(t+1) ----
    a0 = RD(As, raM[0], 0); a1 = RD(As, raM[1], 0);
    b0 = RD(Bs, rbN[0], 0); b1 = RD(Bs, rbN[1], 0);
    if (pf) {
#pragma unroll
      for (int it = 0; it < 4; ++it) gload_lds16(Agp + goff[it] + kb, Ld + lofs[it]);
    }
    __builtin_amdgcn_s_barrier();
    __builtin_amdgcn_s_setprio(1);
    acc[0][0] = MFMA8(a0, b0, acc[0][0]); acc[0][1] = MFMA8(a0, b1, acc[0][1]);
    acc[1][0] = MFMA8(a1, b0, acc[1][0]); acc[1][1] = MFMA8(a1, b1, acc[1][1]);
    __builtin_amdgcn_s_setprio(0);
    __builtin_amdgcn_s_barrier();

    // ---- phase 1: ks=0, n=2,3; stage B(t+1) ----
    b0 = RD(Bs, rbN[2], 0); b1 = RD(Bs, rbN[3], 0);
    if (pf) {
#pragma unroll
      for (int it = 0; it < 4; ++it) gload_lds16(Bgp + goff[it] + kb, Ld + 32768 + lofs[it]);
    }
    __builtin_amdgcn_s_barrier();
    __builtin_amdgcn_s_setprio(1);
    acc[0][2] = MFMA8(a0, b0, acc[0][2]); acc[0][3] = MFMA8(a0, b1, acc[0][3]);
    acc[1][2] = MFMA8(a1, b0, acc[1][2]); acc[1][3] = MFMA8(a1, b1, acc[1][3]);
    __builtin_amdgcn_s_setprio(0);
    __builtin_amdgcn_s_barrier();

    // ---- phase 2: ks=1, n=0,1 ----
    a0 = RD(As, raM[0], 1); a1 = RD(As, raM[1], 1);
    b0 = RD(Bs, rbN[0], 1); b1 = RD(Bs, rbN[1], 1);
    __builtin_amdgcn_s_barrier();
    __builtin_amdgcn_s_setprio(1);
    acc[0][0] = MFMA8(a0, b0, acc[0][0]); acc[0][1] = MFMA8(a0, b1, acc[0][1]);
    acc[1][0] = MFMA8(a1, b0, acc[1][0]); acc[1][1] = MFMA8(a1, b1, acc[1][1]);
    __builtin_amdgcn_s_setprio(0);
    __builtin_amdgcn_s_barrier();

    // ---- phase 3: ks=1, n=2,3; drain next tile's loads ----
    b0 = RD(Bs, rbN[2], 1); b1 = RD(Bs, rbN[3], 1);
    __builtin_amdgcn_s_barrier();
    __builtin_amdgcn_s_setprio(1);
    acc[0][2] = MFMA8(a0, b0, acc[0][2]); acc[0][3] = MFMA8(a0, b1, acc[0][3]);
    acc[1][2] = MFMA8(a1, b0, acc[1][2]); acc[1][3] = MFMA8(a1, b1, acc[1][3]);
    __builtin_amdgcn_s_setprio(0);
    if (pf) asm volatile("s_waitcnt vmcnt(0)" ::: "memory");
    __builtin_amdgcn_s_barrier();
  }

  // ---- epilogue: undo W x64 pre-scale, bias, LSE partial + target grab ----
  const float inv64 = 0.015625f;
  float bv[4];
#pragma unroll
  for (int n = 0; n < 4; ++n) bv[n] = bias[n0 + wn * 128 + n * 32 + l31];

  float4* mrg = (float4*)lds[0];   // [256 rows][2 wn] — all vmem drained
#pragma unroll
  for (int m = 0; m < 2; ++m)
#pragma unroll
    for (int rg = 0; rg < 16; ++rg) {
      float x0 = acc[m][0][rg] * inv64 + bv[0];
      float x1 = acc[m][1][rg] * inv64 + bv[1];
      float x2 = acc[m][2][rg] * inv64 + bv[2];
      float x3 = acc[m][3][rg] * inv64 + bv[3];
      float tmax = fmaxf(fmaxf(x0, x1), fmaxf(x2, x3));
#pragma unroll
      for (int d = 1; d <= 16; d <<= 1) tmax = fmaxf(tmax, __shfl_xor(tmax, d));
      float tsum = __expf(x0 - tmax) + __expf(x1 - tmax) + __expf(x2 - tmax) + __expf(x3 - tmax);
#pragma unroll
      for (int d = 1; d <= 16; d <<= 1) tsum += __shfl_xor(tsum, d);
      // this register's row (depends on lane half h)
      int rr = (rg & 3) + 8 * (rg >> 2) + 4 * h;
      int lrow = wm * 64 + m * 32 + rr;
      int tv = target[rowbase + lrow];
      int c = ((tv == IGNORE_INDEX) ? 0 : tv) - (n0 + wn * 128);  // in [0,128)?
      float rt = 0.f;
      rt += ((c >> 5) == 0 && (c & 31) == l31) ? x0 : 0.f;
      rt += ((c >> 5) == 1 && (c & 31) == l31) ? x1 : 0.f;
      rt += ((c >> 5) == 2 && (c & 31) == l31) ? x2 : 0.f;
      rt += ((c >> 5) == 3 && (c & 31) == l31) ? x3 : 0.f;
#pragma unroll
      for (int d = 1; d <= 16; d <<= 1) rt += __shfl_xor(rt, d);
      if (l31 == 0) mrg[lrow * 2 + wn] = float4{tmax, tsum, rt, 0.f};
    }
  __syncthreads();
  if (tid < BM) {
    float4 p0 = mrg[tid * 2 + 0], p1 = mrg[tid * 2 + 1];
    float mm = fmaxf(p0.x, p1.x);
    float ss = p0.y * __expf(p0.x - mm) + p1.y * __expf(p1.x - mm);
    partials[(size_t)split * kM + rowbase + tid] = float4{mm, ss, p0.z + p1.z, 0.f};
  }
#undef MFMA8
}

// ---------------- combine split partials -> per-token logp ----------------
// one wave per row; 64 lanes strided over splits, shfl LSE-merge. grid = kM/4.
__global__ __launch_bounds__(256) void combine_lse(
    const float4* __restrict__ partials, float* __restrict__ per_tok, int nsplit)
{
  int row  = blockIdx.x * 4 + (threadIdx.x >> 6);
  int lane = threadIdx.x & 63;
  float m = -1e30f, s = 0.f, t = 0.f;
  for (int sp = lane; sp < nsplit; sp += 64) {
    float4 p = partials[(size_t)sp * kM + row];
    t += p.z;
    float nm = fmaxf(m, p.x);
    s = s * __expf(m - nm) + p.y * __expf(p.x - nm);
    m = nm;
  }
#pragma unroll
  for (int d = 1; d < 64; d <<= 1) {
    float mo = __shfl_xor(m, d), so = __shfl_xor(s, d), to = __shfl_xor(t, d);
    float nm = fmaxf(m, mo);
    s = s * __expf(m - nm) + so * __expf(mo - nm);
    m = nm; t += to;
  }
  if (lane == 0) per_tok[row] = t - (m + logf(s));
}

// ---------------- final scalar loss ----------------
__global__ __launch_bounds__(1024) void final_loss(
    const float* __restrict__ per_tok, const int* __restrict__ target, float* __restrict__ out)
{
  __shared__ float redv[16], redc[16];
  __shared__ float ssum[8], scnt[8];
  int t = threadIdx.x;
  int wid = t >> 6, lane = t & 63;
  for (int b = 0; b < 8; ++b) {
    int row = b * 1024 + t;
    float mk = (target[row] != IGNORE_INDEX) ? 1.f : 0.f;
    float v = per_tok[row] * mk;
#pragma unroll
    for (int d = 1; d <= 32; d <<= 1) { v += __shfl_xor(v, d); mk += __shfl_xor(mk, d); }
    if (lane == 0) { redv[wid] = v; redc[wid] = mk; }
    __syncthreads();
    if (t == 0) {
      float sv = 0.f, sc = 0.f;
      for (int j = 0; j < 16; ++j) { sv += redv[j]; sc += redc[j]; }
      ssum[b] = sv; scnt[b] = sc;
    }
    __syncthreads();
  }
  if (t == 0) {
    float nsum = 0.f, ncnt = 0.f;
    for (int b = 0; b < 4; ++b) { nsum += ssum[b]; ncnt += scnt[b]; }
    float nll = -nsum / ncnt;
    float pref = 0.f;
    for (int b = 0; b < 4; ++b) {
      float avc = ssum[b] / scnt[b];
      float avr = ssum[b + 4] / scnt[b + 4];
      float d = 0.1f * (avc - avr);                 // BETA = 0.1
      float ls = (d >= 0.f) ? -log1pf(__expf(-d)) : d - log1pf(__expf(d));
      pref += ls;
    }
    pref *= 0.25f;                                  // mean over 4 pairs
    out[0] = 1.0f * nll - pref;                     // ALPHA = 1.0
  }
}

extern "C" void kernel_launch(void* const* d_in, const int* in_sizes, int n_in,
                              void* d_out, int out_size, void* d_ws, size_t ws_size,
                              hipStream_t stream) {
  const float* lin_weight = (const float*)d_in[0];  // [V][H]
  const float* input      = (const float*)d_in[1];  // [B2][T][H]
  const int*   target     = (const int*)d_in[2];    // [B2][T]
  const float* bias       = (const float*)d_in[3];  // [V]
  float* out = (float*)d_out;

  uint8_t* ws = (uint8_t*)d_ws;
  size_t offW = 0;
  size_t offA = offW + (size_t)kV * kH;                // 65,536,000 B (fp8)
  size_t offP = offA + (size_t)kM * kH;                // +16,777,216 B
  size_t offT = offP + (size_t)NSPLIT * kM * 16;       // +16,384,000 B
  size_t need = offT + (size_t)kM * 4;
  if (ws_size < need) return;  // clean failure signal (output stays 0)

  uint8_t* Wb = ws + offW;
  uint8_t* Ab = ws + offA;
  float4* partials = (float4*)(ws + offP);
  float*  per_tok  = (float*)(ws + offT);

  // W pre-scaled by 64 (escape e4m3 denormals; undone by inv64 in epilogue)
  cast_to_fp8<<<2048, 256, 0, stream>>>(lin_weight, (uint2*)Wb, kV * kH / 8, 64.0f);
  cast_to_fp8<<<1024, 256, 0, stream>>>(input, (uint2*)Ab, kM * kH / 8, 1.0f);
  fused_lse<<<NWG, 512, 0, stream>>>(Wb, Ab, bias, target, partials);
  combine_lse<<<kM / 4, 256, 0, stream>>>(partials, per_tok, NSPLIT);
  final_loss<<<1, 1024, 0, stream>>>(per_tok, target, out);
}

// Round 9
// 683.689 us; speedup vs baseline: 1.5773x; 1.1557x over previous
//
#include <hip/hip_runtime.h>
#include <hip/hip_bf16.h>
#include <stdint.h>

#define IGNORE_INDEX (-100)

constexpr int kB2 = 8, kT = 1024, kH = 2048, kV = 32000;
constexpr int kM = kB2 * kT;           // 8192 token rows
constexpr int BM = 256, BN = 256, BK = 128;   // fp8: 128-B rows
constexpr int NSPLIT = 125;            // vocab splits (1 N-tile each)
constexpr int MBLKS = kM / BM;         // 32 row blocks
constexpr int KT = kH / BK;            // 16 K-tiles
constexpr int NWG = NSPLIT * MBLKS;    // 4000 workgroups

typedef int   i32x4  __attribute__((ext_vector_type(4)));
typedef int   i32x8  __attribute__((ext_vector_type(8)));
typedef float f32x4  __attribute__((ext_vector_type(4)));

// ---------------- cast fp32 -> fp8 e4m3 (OCP), optional pre-scale ----------------
__global__ void cast_to_fp8(const float* __restrict__ src, uint2* __restrict__ dst,
                            int n8, float scale) {
  int idx = blockIdx.x * blockDim.x + threadIdx.x;
  int stride = gridDim.x * blockDim.x;
  const float4* s = (const float4*)src;
  for (int i = idx; i < n8; i += stride) {
    float4 v0 = s[2 * i], v1 = s[2 * i + 1];
    int lo = 0, hi = 0;
    lo = __builtin_amdgcn_cvt_pk_fp8_f32(v0.x * scale, v0.y * scale, lo, false);
    lo = __builtin_amdgcn_cvt_pk_fp8_f32(v0.z * scale, v0.w * scale, lo, true);
    hi = __builtin_amdgcn_cvt_pk_fp8_f32(v1.x * scale, v1.y * scale, hi, false);
    hi = __builtin_amdgcn_cvt_pk_fp8_f32(v1.z * scale, v1.w * scale, hi, true);
    dst[i] = uint2{(unsigned)lo, (unsigned)hi};
  }
}

__device__ __forceinline__ void gload_lds16(const void* g, void* l) {
  __builtin_amdgcn_global_load_lds(
      (const __attribute__((address_space(1))) void*)g,
      (__attribute__((address_space(3))) void*)l, 16, 0, 0);
}

// ---------------- fused fp8 GEMM + logsumexp + target grab ----------------
// 256x256x128 tile, 8 waves (4M x 2N; wave = 64 rows x 128 cols), 2 LDS dbuf.
// MFMA: mfma_scale_f32_16x16x128_f8f6f4 (fp8 x fp8, unit e8m0 scales 0x7F).
// Shape choice vs r8's 32x32x64: SAME rate/FLOP, but operand reads span only
// 16 rows per ds_read_b128 (row = lane&15, chunks 2*(lane>>4)+{0,1}) — the
// bf16-proven conflict-free pattern. r8's 32-row span caused 49.4M bank
// conflicts (4 lanes per swizzled chunk); this eliminates them.
// Wave frags: 4 (M,16) x 8 (N,16); 32 MFMA per K-tile, 8 per phase.
// 4 phases/K-tile, 2 barriers each, setprio around MFMA (T5), stage A at ph0 /
// B at ph1, vmcnt(0) drain at ph3 (counted waits proven neutral r7).
// LDS layout per buffer: A[256][128B] | B[256][128B]; chunk (row,j) holds
// global chunk (row, j^(row&7)) — pre-swizzled source, swizzled read (#21).
// C-layout 16x16 (dtype-independent, m89): col = lane&15, row = (lane>>4)*4+reg.
// Block->(split,mblk) map unchanged (XCD-affinity; FETCH 388MB proven r8).
__global__ __launch_bounds__(512, 2) void fused_lse(
    const uint8_t* __restrict__ Wb,  // [V][H] fp8 (pre-scaled by 64)
    const uint8_t* __restrict__ Ab,  // [M][H] fp8
    const float* __restrict__ bias,  // [V]
    const int* __restrict__ target,  // [M]
    float4* __restrict__ partials)   // [NSPLIT][M] : (m, s, tgt_logit, 0)
{
  const int bid = blockIdx.x;
  const int gg = bid >> 8, r = bid & 255;
  int split, mblk;
  if (gg < 15) { int j = r >> 3; split = gg * 8 + (j & 7); mblk = (r & 7) * 4 + (j >> 3); }
  else         { split = 120 + (r >> 5); mblk = r & 31; }   // last group: 5 splits x 32

  const int tid = threadIdx.x;
  const int lane = tid & 63;
  const int w  = tid >> 6;     // 0..7
  const int wm = w >> 1;       // 0..3 : 64-row band
  const int wn = w & 1;        // 0..1 : 128-col half
  const int g  = lane >> 4;    // k-group (reads) / row-group (C layout)
  const int li = lane & 15;
  const int rowbase = mblk * BM;
  const int n0 = split * BN;

  __shared__ __align__(16) uint8_t lds[2][65536];   // per buf: A 32KB | B 32KB

  f32x4 acc[4][8];   // [m][n] : rows wm*64+m*16, cols wn*128+n*16
  const f32x4 vzero = {0.f, 0.f, 0.f, 0.f};
#pragma unroll
  for (int m = 0; m < 4; ++m)
#pragma unroll
    for (int n = 0; n < 8; ++n) acc[m][n] = vzero;

  // staging geometry (A and B tiles: 32 segs of 1KB each; wave w owns segs
  // 4w..4w+3). chunk c = seg*64+lane; row=c>>3, col=c&7; source col ^= row&7.
  int goff[4], lofs[4];
#pragma unroll
  for (int it = 0; it < 4; ++it) {
    int seg = 4 * w + it, c = seg * 64 + lane;
    int row = c >> 3, col = c & 7;
    goff[it] = row * kH + ((col ^ (row & 7)) << 4);   // fp8: row stride = kH bytes
    lofs[it] = seg * 1024;
  }

  const uint8_t* Agp = Ab + (size_t)rowbase * kH;
  const uint8_t* Bgp = Wb + (size_t)n0 * kH;

  // fragment rows
  int raM[4], rbN[8];
#pragma unroll
  for (int m = 0; m < 4; ++m) raM[m] = wm * 64 + m * 16 + li;
#pragma unroll
  for (int n = 0; n < 8; ++n) rbN[n] = wn * 128 + n * 16 + li;

  // read one 32B operand frag: lane's k-bytes [g*32, g*32+32) of row rr
  // (2 consecutive chunks 2g,2g+1, each XOR-swizzled) — 16-row span per instr.
  auto RD = [&](const uint8_t* base, int rr) -> i32x8 {
    int c0 = g * 2;
    union { i32x4 q[2]; i32x8 o; } u;
    u.q[0] = *(const i32x4*)(base + rr * 128 + ((c0 ^ (rr & 7)) << 4));
    u.q[1] = *(const i32x4*)(base + rr * 128 + (((c0 + 1) ^ (rr & 7)) << 4));
    return u.o;
  };

#define MFMA8(am, bn, cc) \
  __builtin_amdgcn_mfma_scale_f32_16x16x128_f8f6f4((am), (bn), (cc), 0, 0, \
      0, 0x7F7F7F7F, 0, 0x7F7F7F7F)

  // prologue: stage tile 0 into buf 0, drain
#pragma unroll
  for (int it = 0; it < 4; ++it) gload_lds16(Agp + goff[it], lds[0] + lofs[it]);
#pragma unroll
  for (int it = 0; it < 4; ++it) gload_lds16(Bgp + goff[it], lds[0] + 32768 + lofs[it]);
  asm volatile("s_waitcnt vmcnt(0)" ::: "memory");
  __builtin_amdgcn_s_barrier();

  for (int t = 0; t < KT; ++t) {
    const uint8_t* As = lds[t & 1];
    const uint8_t* Bs = lds[t & 1] + 32768;
    uint8_t* Ld = lds[(t + 1) & 1];
    const int kb = (t + 1) << 7;         // next tile's K byte offset (128 B)
    const bool pf = (t + 1 < KT);        // workgroup-uniform
    i32x8 af[4], b0, b1;

    // ---- phase 0: A frags + B n=0,1; stage A(t+1) ----
#pragma unroll
    for (int m = 0; m < 4; ++m) af[m] = RD(As, raM[m]);
    b0 = RD(Bs, rbN[0]); b1 = RD(Bs, rbN[1]);
    if (pf) {
#pragma unroll
      for (int it = 0; it < 4; ++it) gload_lds16(Agp + goff[it] + kb, Ld + lofs[it]);
    }
    __builtin_amdgcn_s_barrier();
    __builtin_amdgcn_s_setprio(1);
#pragma unroll
    for (int m = 0; m < 4; ++m) {
      acc[m][0] = MFMA8(af[m], b0, acc[m][0]);
      acc[m][1] = MFMA8(af[m], b1, acc[m][1]);
    }
    __builtin_amdgcn_s_setprio(0);
    __builtin_amdgcn_s_barrier();

    // ---- phase 1: B n=2,3; stage B(t+1) ----
    b0 = RD(Bs, rbN[2]); b1 = RD(Bs, rbN[3]);
    if (pf) {
#pragma unroll
      for (int it = 0; it < 4; ++it) gload_lds16(Bgp + goff[it] + kb, Ld + 32768 + lofs[it]);
    }
    __builtin_amdgcn_s_barrier();
    __builtin_amdgcn_s_setprio(1);
#pragma unroll
    for (int m = 0; m < 4; ++m) {
      acc[m][2] = MFMA8(af[m], b0, acc[m][2]);
      acc[m][3] = MFMA8(af[m], b1, acc[m][3]);
    }
    __builtin_amdgcn_s_setprio(0);
    __builtin_amdgcn_s_barrier();

    // ---- phase 2: B n=4,5 ----
    b0 = RD(Bs, rbN[4]); b1 = RD(Bs, rbN[5]);
    __builtin_amdgcn_s_barrier();
    __builtin_amdgcn_s_setprio(1);
#pragma unroll
    for (int m = 0; m < 4; ++m) {
      acc[m][4] = MFMA8(af[m], b0, acc[m][4]);
      acc[m][5] = MFMA8(af[m], b1, acc[m][5]);
    }
    __builtin_amdgcn_s_setprio(0);
    __builtin_amdgcn_s_barrier();

    // ---- phase 3: B n=6,7; drain next tile's loads ----
    b0 = RD(Bs, rbN[6]); b1 = RD(Bs, rbN[7]);
    __builtin_amdgcn_s_barrier();
    __builtin_amdgcn_s_setprio(1);
#pragma unroll
    for (int m = 0; m < 4; ++m) {
      acc[m][6] = MFMA8(af[m], b0, acc[m][6]);
      acc[m][7] = MFMA8(af[m], b1, acc[m][7]);
    }
    __builtin_amdgcn_s_setprio(0);
    if (pf) asm volatile("s_waitcnt vmcnt(0)" ::: "memory");
    __builtin_amdgcn_s_barrier();
  }

  // ---- epilogue: undo W x64 pre-scale, bias, LSE partial + target grab ----
  const float inv64 = 0.015625f;
  float bv[8];
#pragma unroll
  for (int n = 0; n < 8; ++n) bv[n] = bias[n0 + wn * 128 + n * 16 + li];

  float4* mrg = (float4*)lds[0];   // [256 rows][2 wn] — all vmem drained
#pragma unroll
  for (int m = 0; m < 4; ++m)
#pragma unroll
    for (int i = 0; i < 4; ++i) {
      float x[8];
#pragma unroll
      for (int n = 0; n < 8; ++n) x[n] = acc[m][n][i] * inv64 + bv[n];
      float tmax = x[0];
#pragma unroll
      for (int n = 1; n < 8; ++n) tmax = fmaxf(tmax, x[n]);
#pragma unroll
      for (int d = 1; d <= 8; d <<= 1) tmax = fmaxf(tmax, __shfl_xor(tmax, d));
      float tsum = 0.f;
#pragma unroll
      for (int n = 0; n < 8; ++n) tsum += __expf(x[n] - tmax);
#pragma unroll
      for (int d = 1; d <= 8; d <<= 1) tsum += __shfl_xor(tsum, d);
      int lrow = wm * 64 + m * 16 + g * 4 + i;
      int tv = target[rowbase + lrow];
      int c = ((tv == IGNORE_INDEX) ? 0 : tv) - (n0 + wn * 128);  // in [0,128)?
      float rt = 0.f;
#pragma unroll
      for (int n = 0; n < 8; ++n)
        rt += ((c >> 4) == n && (c & 15) == li) ? x[n] : 0.f;
#pragma unroll
      for (int d = 1; d <= 8; d <<= 1) rt += __shfl_xor(rt, d);
      if (li == 0) mrg[lrow * 2 + wn] = float4{tmax, tsum, rt, 0.f};
    }
  __syncthreads();
  if (tid < BM) {
    float4 p0 = mrg[tid * 2 + 0], p1 = mrg[tid * 2 + 1];
    float mm = fmaxf(p0.x, p1.x);
    float ss = p0.y * __expf(p0.x - mm) + p1.y * __expf(p1.x - mm);
    partials[(size_t)split * kM + rowbase + tid] = float4{mm, ss, p0.z + p1.z, 0.f};
  }
#undef MFMA8
}

// ---------------- combine split partials -> per-token logp ----------------
// one wave per row; 64 lanes strided over splits, shfl LSE-merge. grid = kM/4.
__global__ __launch_bounds__(256) void combine_lse(
    const float4* __restrict__ partials, float* __restrict__ per_tok, int nsplit)
{
  int row  = blockIdx.x * 4 + (threadIdx.x >> 6);
  int lane = threadIdx.x & 63;
  float m = -1e30f, s = 0.f, t = 0.f;
  for (int sp = lane; sp < nsplit; sp += 64) {
    float4 p = partials[(size_t)sp * kM + row];
    t += p.z;
    float nm = fmaxf(m, p.x);
    s = s * __expf(m - nm) + p.y * __expf(p.x - nm);
    m = nm;
  }
#pragma unroll
  for (int d = 1; d < 64; d <<= 1) {
    float mo = __shfl_xor(m, d), so = __shfl_xor(s, d), to = __shfl_xor(t, d);
    float nm = fmaxf(m, mo);
    s = s * __expf(m - nm) + so * __expf(mo - nm);
    m = nm; t += to;
  }
  if (lane == 0) per_tok[row] = t - (m + logf(s));
}

// ---------------- final scalar loss ----------------
__global__ __launch_bounds__(1024) void final_loss(
    const float* __restrict__ per_tok, const int* __restrict__ target, float* __restrict__ out)
{
  __shared__ float redv[16], redc[16];
  __shared__ float ssum[8], scnt[8];
  int t = threadIdx.x;
  int wid = t >> 6, lane = t & 63;
  for (int b = 0; b < 8; ++b) {
    int row = b * 1024 + t;
    float mk = (target[row] != IGNORE_INDEX) ? 1.f : 0.f;
    float v = per_tok[row] * mk;
#pragma unroll
    for (int d = 1; d <= 32; d <<= 1) { v += __shfl_xor(v, d); mk += __shfl_xor(mk, d); }
    if (lane == 0) { redv[wid] = v; redc[wid] = mk; }
    __syncthreads();
    if (t == 0) {
      float sv = 0.f, sc = 0.f;
      for (int j = 0; j < 16; ++j) { sv += redv[j]; sc += redc[j]; }
      ssum[b] = sv; scnt[b] = sc;
    }
    __syncthreads();
  }
  if (t == 0) {
    float nsum = 0.f, ncnt = 0.f;
    for (int b = 0; b < 4; ++b) { nsum += ssum[b]; ncnt += scnt[b]; }
    float nll = -nsum / ncnt;
    float pref = 0.f;
    for (int b = 0; b < 4; ++b) {
      float avc = ssum[b] / scnt[b];
      float avr = ssum[b + 4] / scnt[b + 4];
      float d = 0.1f * (avc - avr);                 // BETA = 0.1
      float ls = (d >= 0.f) ? -log1pf(__expf(-d)) : d - log1pf(__expf(d));
      pref += ls;
    }
    pref *= 0.25f;                                  // mean over 4 pairs
    out[0] = 1.0f * nll - pref;                     // ALPHA = 1.0
  }
}

extern "C" void kernel_launch(void* const* d_in, const int* in_sizes, int n_in,
                              void* d_out, int out_size, void* d_ws, size_t ws_size,
                              hipStream_t stream) {
  const float* lin_weight = (const float*)d_in[0];  // [V][H]
  const float* input      = (const float*)d_in[1];  // [B2][T][H]
  const int*   target     = (const int*)d_in[2];    // [B2][T]
  const float* bias       = (const float*)d_in[3];  // [V]
  float* out = (float*)d_out;

  uint8_t* ws = (uint8_t*)d_ws;
  size_t offW = 0;
  size_t offA = offW + (size_t)kV * kH;                // 65,536,000 B (fp8)
  size_t offP = offA + (size_t)kM * kH;                // +16,777,216 B
  size_t offT = offP + (size_t)NSPLIT * kM * 16;       // +16,384,000 B
  size_t need = offT + (size_t)kM * 4;
  if (ws_size < need) return;  // clean failure signal (output stays 0)

  uint8_t* Wb = ws + offW;
  uint8_t* Ab = ws + offA;
  float4* partials = (float4*)(ws + offP);
  float*  per_tok  = (float*)(ws + offT);

  // W pre-scaled by 64 (escape e4m3 denormals; undone by inv64 in epilogue)
  cast_to_fp8<<<2048, 256, 0, stream>>>(lin_weight, (uint2*)Wb, kV * kH / 8, 64.0f);
  cast_to_fp8<<<1024, 256, 0, stream>>>(input, (uint2*)Ab, kM * kH / 8, 1.0f);
  fused_lse<<<NWG, 512, 0, stream>>>(Wb, Ab, bias, target, partials);
  combine_lse<<<kM / 4, 256, 0, stream>>>(partials, per_tok, NSPLIT);
  final_loss<<<1, 1024, 0, stream>>>(per_tok, target, out);
}